// Round 14
// baseline (300.991 us; speedup 1.0000x reference)
//
#include <hip/hip_runtime.h>
#include <hip/hip_bf16.h>

typedef __hip_bfloat16 bf16;
typedef unsigned short us8 __attribute__((ext_vector_type(8)));
typedef __attribute__((ext_vector_type(8))) short short8v;
typedef __attribute__((ext_vector_type(4))) float float4v;

__device__ __forceinline__ float us2f(unsigned short u){
  return __uint_as_float(((unsigned int)u) << 16);
}
__device__ __forceinline__ float b2f(bf16 v){ return __bfloat162float(v); }
__device__ __forceinline__ bf16 f2b(float v){ return __float2bfloat16(v); }
__device__ __forceinline__ unsigned short f2bu(float v){
  bf16 t = f2b(v); return *reinterpret_cast<unsigned short*>(&t);
}

#define HW 9216
#define CH 512
#define NQ 640   /* 64 q | 64 k | 512 v packed along output-channel axis */

// -------- dtype detector: flag=1 if x is bf16-packed, 0 if f32 ------------
__global__ void k_detect(const unsigned int* __restrict__ xw, int* __restrict__ flag){
  int t = threadIdx.x;    // 256 threads, 1 block
  int cnt = 0;
  for(int i=t;i<4096;i+=256){
    unsigned e = (xw[i]>>8)&0x7F;
    if(e==0x3E||e==0x3F) cnt++;
  }
  #pragma unroll
  for(int o=32;o>0;o>>=1) cnt += __shfl_xor(cnt,o);
  __shared__ int s[4];
  if((t&63)==0) s[t>>6]=cnt;
  __syncthreads();
  if(t==0){ int tot=s[0]+s[1]+s[2]+s[3]; *flag = (tot > 1228) ? 1 : 0; }
}

// ---------------- pack Wq|Wk|Wv (640x512) + f32 biases ----------------
__global__ void k_pack(const void* __restrict__ Wq, const void* __restrict__ Wk,
                       const void* __restrict__ Wv, const void* __restrict__ bq,
                       const void* __restrict__ bk, const void* __restrict__ bv,
                       const int* __restrict__ flag,
                       bf16* __restrict__ Wall, float* __restrict__ ball){
  bool isbf = (*flag)!=0;
  int j = blockIdx.x, t = threadIdx.x;
  const void* src = (j < 64) ? Wq : (j < 128) ? Wk : Wv;
  int row = (j < 64) ? j : (j < 128) ? (j-64) : (j-128);
  for(int c=t;c<512;c+=256){
    float v = isbf ? b2f(((const bf16*)src)[(size_t)row*512+c])
                   : ((const float*)src)[(size_t)row*512+c];
    Wall[(size_t)j*512+c] = f2b(v);
  }
  if(t==0){
    const void* bsrc = (j<64)? bq : (j<128)? bk : bv;
    ball[j] = isbf ? b2f(((const bf16*)bsrc)[row]) : ((const float*)bsrc)[row];
  }
}

// ---------------- x[b][c][hw] (f32/bf16) -> xT[b][hw][c] (bf16), vectorized
__global__ __launch_bounds__(256) void k_xcvt(const void* __restrict__ x,
    const int* __restrict__ flag, bf16* __restrict__ xT){
  __shared__ float T[64][65];      // [c][hw]
  bool isbf = (*flag)!=0;
  int b = blockIdx.z, c0 = blockIdx.y*64, hw0 = blockIdx.x*64;
  int tid = threadIdx.x;
  if(isbf){
    const bf16* xb = (const bf16*)x + ((size_t)b*CH + c0)*HW + hw0;
    #pragma unroll
    for(int i=0;i<2;i++){
      int e = i*256 + tid;           // 0..511
      int cc = e>>3, h8 = (e&7)*8;
      us8 v = *(const us8*)(xb + (size_t)cc*HW + h8);
      #pragma unroll
      for(int j=0;j<8;j++) T[cc][h8+j] = us2f(v[j]);
    }
  } else {
    const float* xb = (const float*)x + ((size_t)b*CH + c0)*HW + hw0;
    #pragma unroll
    for(int i=0;i<4;i++){
      int e = i*256 + tid;           // 0..1023
      int cc = e>>4, h4 = (e&15)*4;
      float4 v = *(const float4*)(xb + (size_t)cc*HW + h4);
      T[cc][h4]=v.x; T[cc][h4+1]=v.y; T[cc][h4+2]=v.z; T[cc][h4+3]=v.w;
    }
  }
  __syncthreads();
  bf16* tb = xT + ((size_t)b*HW + hw0)*512 + c0;
  #pragma unroll
  for(int i=0;i<2;i++){
    int e = i*256 + tid;             // 0..511
    int r = e>>3, c8 = (e&7)*8;
    us8 o;
    #pragma unroll
    for(int j=0;j<8;j++) o[j] = f2bu(T[c8+j][r]);
    *(us8*)(tb + (size_t)r*512 + c8) = o;
  }
}

// ---------------- QKV GEMM (MFMA): Ot[b][hw][j] = sum_c xT[hw][c]*Wall[j][c]+b[j]
// M=9216 N=640 K=512; tile 128x128x64; 256 thr = 4 waves (2x2), each 64x64
__global__ __launch_bounds__(256) void k_qkv(const bf16* __restrict__ xT,
    const bf16* __restrict__ Wall, const float* __restrict__ ball,
    bf16* __restrict__ Ot){
  __shared__ ushort As[128][72];   // [m][k]
  __shared__ ushort Bs[128][72];   // [n][k]
  int b = blockIdx.y;
  int bx = blockIdx.x;                 // 0..359
  int swz = (bx & 7)*45 + (bx >> 3);   // XCD-chunk: 5 n-siblings stay on one XCD
  int m0 = (swz/5)*128;
  int n0 = (swz%5)*128;
  int tid = threadIdx.x, wid = tid>>6, lane = tid&63;
  int m0w = (wid>>1)*64, n0w = (wid&1)*64;
  const bf16* Ab = xT + ((size_t)b*HW + m0)*512;
  const bf16* Bb = Wall + (size_t)n0*512;
  float4v acc[4][4];
  #pragma unroll
  for(int mt=0;mt<4;mt++)
    #pragma unroll
    for(int nt=0;nt<4;nt++) acc[mt][nt] = (float4v){0.f,0.f,0.f,0.f};
  for(int k0=0;k0<512;k0+=64){
    #pragma unroll
    for(int i=0;i<4;i++){
      int s = tid + i*256;
      int row = s>>3, ko = (s&7)*8;
      us8 v = *(const us8*)(Ab + (size_t)row*512 + k0 + ko);
      *(us8*)&As[row][ko] = v;
      us8 w = *(const us8*)(Bb + (size_t)row*512 + k0 + ko);
      *(us8*)&Bs[row][ko] = w;
    }
    __syncthreads();
    #pragma unroll
    for(int kk=0;kk<64;kk+=32){
      short8v a[4], bb[4];
      #pragma unroll
      for(int mt=0;mt<4;mt++) a[mt] = *(short8v*)&As[m0w+mt*16+(lane&15)][kk+8*(lane>>4)];
      #pragma unroll
      for(int nt=0;nt<4;nt++) bb[nt] = *(short8v*)&Bs[n0w+nt*16+(lane&15)][kk+8*(lane>>4)];
      #pragma unroll
      for(int mt=0;mt<4;mt++)
        #pragma unroll
        for(int nt=0;nt<4;nt++)
          acc[mt][nt] = __builtin_amdgcn_mfma_f32_16x16x32_bf16(a[mt], bb[nt], acc[mt][nt], 0,0,0);
    }
    __syncthreads();
  }
  #pragma unroll
  for(int mt=0;mt<4;mt++){
    #pragma unroll
    for(int nt=0;nt<4;nt++){
      int nn = n0 + n0w + nt*16 + (lane&15);
      float bias = ball[nn];
      int mbase = m0 + m0w + mt*16 + (lane>>4)*4;
      #pragma unroll
      for(int r=0;r<4;r++)
        Ot[((size_t)b*HW + mbase + r)*640 + nn] = f2b(acc[mt][nt][r] + bias);
    }
  }
}

// ---- e_h (MFMA) per (b,w): eh2[(h*96+w)][g] = q(h,w).k(g,w), diag=-inf ----
// M=96(h) N=96(g) K=64; rows of Ot strided by 96*640; 384 thr = 6 waves
__global__ __launch_bounds__(384) void k_eh(const bf16* __restrict__ Ot,
                                            float* __restrict__ eh2){
  __shared__ ushort Qs[96][72];
  __shared__ ushort Ks[96][72];
  int b = blockIdx.y, w = blockIdx.x;
  int tid = threadIdx.x, wid = tid>>6, lane = tid&63;
  const bf16* qb = Ot + ((size_t)b*HW + w)*640;
  #pragma unroll
  for(int i=0;i<2;i++){
    int e = tid + i*384;             // 0..767
    int row = e>>3, ko = (e&7)*8;
    us8 q = *(const us8*)(qb + (size_t)row*96*640 + ko);
    *(us8*)&Qs[row][ko] = q;
    us8 k = *(const us8*)(qb + (size_t)row*96*640 + 64 + ko);
    *(us8*)&Ks[row][ko] = k;
  }
  __syncthreads();
  float4v acc[6];
  #pragma unroll
  for(int nt=0;nt<6;nt++) acc[nt] = (float4v){0.f,0.f,0.f,0.f};
  #pragma unroll
  for(int kt=0;kt<2;kt++){
    int kb = kt*32 + 8*(lane>>4);
    short8v a = *(short8v*)&Qs[wid*16 + (lane&15)][kb];
    #pragma unroll
    for(int nt=0;nt<6;nt++){
      short8v bb = *(short8v*)&Ks[nt*16 + (lane&15)][kb];
      acc[nt] = __builtin_amdgcn_mfma_f32_16x16x32_bf16(a, bb, acc[nt], 0,0,0);
    }
  }
  int hbase = wid*16 + (lane>>4)*4;
  #pragma unroll
  for(int nt=0;nt<6;nt++){
    int g = nt*16 + (lane&15);
    #pragma unroll
    for(int r=0;r<4;r++){
      int h = hbase + r;
      eh2[((size_t)b*HW + (size_t)h*96 + w)*96 + g] =
          (g==h) ? -INFINITY : acc[nt][r];
    }
  }
}

// ---- fused e_w + softmax per (b,h): e_w in LDS, e_h from compact buffer ---
// M=96(w) N=96(v) K=64 MFMA, then row-softmax over [e_h(96) | e_w(96)].
// LDS union: Qs+Ks (27.6KB, dead after MFMA) overlap Ew (38.4KB) -> 4 blk/CU.
__global__ __launch_bounds__(384) void k_ewsm(const bf16* __restrict__ Ot,
    const float* __restrict__ eh2, bf16* __restrict__ att){
  __shared__ char smem[38400];
  ushort (*Qs)[72] = (ushort(*)[72])smem;            // 13824 B
  ushort (*Ks)[72] = (ushort(*)[72])(smem + 13824);  // 13824 B
  float  (*Ew)[100] = (float(*)[100])smem;           // 38400 B (reuses all)
  int b = blockIdx.y, h = blockIdx.x;
  int tid = threadIdx.x, wid = tid>>6, lane = tid&63;
  const bf16* qb = Ot + ((size_t)b*HW + (size_t)h*96)*640;
  #pragma unroll
  for(int i=0;i<2;i++){
    int e = tid + i*384;             // 0..767
    int row = e>>3, ko = (e&7)*8;
    us8 q = *(const us8*)(qb + (size_t)row*640 + ko);
    *(us8*)&Qs[row][ko] = q;
    us8 k = *(const us8*)(qb + (size_t)row*640 + 64 + ko);
    *(us8*)&Ks[row][ko] = k;
  }
  __syncthreads();
  float4v acc[6];
  #pragma unroll
  for(int nt=0;nt<6;nt++) acc[nt] = (float4v){0.f,0.f,0.f,0.f};
  #pragma unroll
  for(int kt=0;kt<2;kt++){
    int kb = kt*32 + 8*(lane>>4);
    short8v a = *(short8v*)&Qs[wid*16 + (lane&15)][kb];
    #pragma unroll
    for(int nt=0;nt<6;nt++){
      short8v bb = *(short8v*)&Ks[nt*16 + (lane&15)][kb];
      acc[nt] = __builtin_amdgcn_mfma_f32_16x16x32_bf16(a, bb, acc[nt], 0,0,0);
    }
  }
  __syncthreads();                   // all waves done READING Qs/Ks
  int wbase = wid*16 + (lane>>4)*4;
  #pragma unroll
  for(int nt=0;nt<6;nt++){
    int v = nt*16 + (lane&15);
    #pragma unroll
    for(int r=0;r<4;r++) Ew[wbase+r][v] = acc[nt][r];
  }
  __syncthreads();
  const float* ehb = eh2 + ((size_t)b*HW + (size_t)h*96)*96;
  bf16* ab = att + ((size_t)b*HW + (size_t)h*96)*192;
  for(int r=0;r<16;r++){
    int w = wid*16 + r;
    const float* er = ehb + (size_t)w*96;
    float v0 = er[lane];
    float v1 = (lane<32) ? er[64+lane] : Ew[w][lane-32];
    float v2 = Ew[w][lane+32];
    float m = fmaxf(fmaxf(v0,v1),v2);
    #pragma unroll
    for(int o=32;o>0;o>>=1) m = fmaxf(m, __shfl_xor(m,o));
    v0=__expf(v0-m); v1=__expf(v1-m); v2=__expf(v2-m);
    float s = v0+v1+v2;
    #pragma unroll
    for(int o=32;o>0;o>>=1) s += __shfl_xor(s,o);
    float inv = 1.0f/s;
    bf16* a = ab + (size_t)w*192;
    a[lane]=f2b(v0*inv); a[lane+64]=f2b(v1*inv); a[lane+128]=f2b(v2*inv);
  }
}

// ---- out_h (MFMA): P[b][h*96+w][c] = sum_g a_h[(h,w)][g] * V[(g,w)][c] ----
// per (b,w,c-quarter): M=96(h) N=128(c) K=96(g); pure store (no RMW)
__global__ __launch_bounds__(384) void k_outh(const bf16* __restrict__ Ot,
    const bf16* __restrict__ att, bf16* __restrict__ P){
  __shared__ ushort As[96][104];    // [h][g]
  __shared__ ushort Bs[128][104];   // [c][g]
  int b = blockIdx.y;
  int w = blockIdx.x >> 2, c0 = (blockIdx.x & 3)*128;
  int tid = threadIdx.x, wid = tid>>6, lane = tid&63;
  const bf16* ab = att + ((size_t)b*HW + w)*192;
  #pragma unroll
  for(int i=0;i<3;i++){
    int s = tid + i*384;
    int row = s/12, ko = (s%12)*8;
    us8 v = *(const us8*)(ab + (size_t)row*96*192 + ko);
    *(us8*)&As[row][ko] = v;
  }
  const bf16* vb = Ot + ((size_t)b*HW + w)*640 + 128 + c0;
  #pragma unroll
  for(int i=0;i<4;i++){
    int s = tid + i*384;              // 0..1535
    int g = s % 96, cc = s / 96;      // g-row, c-chunk
    us8 v = *(const us8*)(vb + (size_t)g*96*640 + cc*8);
    #pragma unroll
    for(int j=0;j<8;j++) Bs[cc*8+j][g] = v[j];
  }
  __syncthreads();
  float4v acc[8];
  #pragma unroll
  for(int nt=0;nt<8;nt++) acc[nt] = (float4v){0.f,0.f,0.f,0.f};
  #pragma unroll
  for(int kt=0;kt<3;kt++){
    int kb = kt*32 + 8*(lane>>4);
    short8v a = *(short8v*)&As[wid*16 + (lane&15)][kb];
    #pragma unroll
    for(int nt=0;nt<8;nt++){
      short8v bb = *(short8v*)&Bs[nt*16 + (lane&15)][kb];
      acc[nt] = __builtin_amdgcn_mfma_f32_16x16x32_bf16(a, bb, acc[nt], 0,0,0);
    }
  }
  bf16* Pb = P + ((size_t)b*HW + w)*512 + c0;
  int mb = wid*16 + (lane>>4)*4;
  #pragma unroll
  for(int nt=0;nt<8;nt++){
    int n = nt*16 + (lane&15);
    #pragma unroll
    for(int r=0;r<4;r++){
      size_t o = (size_t)(mb + r)*96*512 + n;
      Pb[o] = f2b(acc[nt][r]);
    }
  }
}

// ---- out_w + final fused (swapped-operand MFMA + LDS epilogue) ------------
// per (b,h,c-EIGHTH): M=64(c) N=96(w) K=96(v); 512 thr = 8 waves (4c x 2w).
// a_w fragments loaded DIRECTLY from global (contiguous, 16B-aligned, L2-hot)
// -> no As staging phase.  Block mapping h=bx%96, ce=bx/96 puts the 8
// c-eighth siblings (sharing att+V) on the SAME XCD (ids congruent mod 8).
// LDS = max(Bs 13.3KB, T 25.6KB) = 25.6KB.  Arithmetic identical to r11-13.
__global__ __launch_bounds__(512) void k_outwf(const bf16* __restrict__ Ot,
    const bf16* __restrict__ att, const bf16* __restrict__ P,
    const void* __restrict__ x, const void* __restrict__ gamma,
    const int* __restrict__ flag, void* __restrict__ out){
  __shared__ char smem[25600];       // A: Bs(13312); B/C: T(25600)
  ushort (*Bs)[104] = (ushort(*)[104])smem;            // [c][v]  (V^T, 64 rows)
  float  (*T)[100]  = (float(*)[100])smem;             // [c][w]  epilogue tile
  bool isbf = (*flag)!=0;
  int b = blockIdx.y;
  int bx = blockIdx.x;
  int h = bx % 96, c0 = (bx / 96)*64;   // XCD-affinity for c-siblings
  int tid = threadIdx.x, wid = tid>>6, lane = tid&63;
  float g = isbf ? b2f(((const bf16*)gamma)[0]) : ((const float*)gamma)[0];
  // stage V^T only (conflict-free scatter, as before)
  const bf16* vb = Ot + ((size_t)b*HW + (size_t)h*96)*640 + 128 + c0;
  #pragma unroll
  for(int i=0;i<2;i++){
    int s = tid + i*512;              // 0..1023
    if(s < 768){
      int gg = s % 96, cc = s / 96;   // v-row, c-chunk (conflict-free scatter)
      us8 v = *(const us8*)(vb + (size_t)gg*640 + cc*8);
      #pragma unroll
      for(int j=0;j<8;j++) Bs[cc*8+j][gg] = v[j];
    }
  }
  __syncthreads();
  // Phase A: MFMA, wave = (c-tile wid>>1, w-half wid&1); acc[3]
  // B-operand (a_w rows) read straight from global: 8 contiguous bf16.
  const bf16* awb = att + ((size_t)b*HW + (size_t)h*96)*192 + 96;
  int mrow = (wid>>1)*16 + (lane&15);
  int ncol0 = (wid&1)*48;
  float4v acc[3];
  #pragma unroll
  for(int nt=0;nt<3;nt++) acc[nt] = (float4v){0.f,0.f,0.f,0.f};
  #pragma unroll
  for(int kt=0;kt<3;kt++){
    int kb = kt*32 + 8*(lane>>4);
    short8v a = *(short8v*)&Bs[mrow][kb];                 // A = V^T (c rows)
    #pragma unroll
    for(int nt=0;nt<3;nt++){
      int wrow = ncol0 + nt*16 + (lane&15);
      short8v bb = *(const short8v*)(awb + (size_t)wrow*192 + kb); // B = a_w
      acc[nt] = __builtin_amdgcn_mfma_f32_16x16x32_bf16(a, bb, acc[nt], 0,0,0);
    }
  }
  __syncthreads();                    // Bs dead; smem becomes T
  // B1: acc -> T[c][w]
  int clb = (wid>>1)*16 + (lane>>4)*4;
  #pragma unroll
  for(int nt=0;nt<3;nt++){
    int w = ncol0 + nt*16 + (lane&15);
    #pragma unroll
    for(int r=0;r<4;r++) T[clb + r][w] = acc[nt][r];
  }
  __syncthreads();
  // B2: T += P_h (us8 reads, conflict-free scatter-add)
  const bf16* Pb = P + ((size_t)b*HW + (size_t)h*96)*512 + c0;
  #pragma unroll
  for(int i=0;i<2;i++){
    int s = tid + i*512;
    if(s < 768){
      int gg = s % 96, cc = s / 96;   // w-row, c-chunk
      us8 v = *(const us8*)(Pb + (size_t)gg*512 + cc*8);
      #pragma unroll
      for(int j=0;j<8;j++) T[cc*8+j][gg] += us2f(v[j]);
    }
  }
  __syncthreads();
  // C: coalesced write-out  out[b][c0+c][h*96+w] = g*T[c][w] + x[...]
  size_t xbase = ((size_t)b*CH + c0)*HW + (size_t)h*96;
  if(isbf){
    const bf16* xb = (const bf16*)x;
    bf16* ob = (bf16*)out;
    #pragma unroll
    for(int i=0;i<2;i++){
      int e = i*512 + tid;            // 0..1023 (64c x 12 us8-chunks = 768)
      if(e < 768){
        int c = e/12, w8 = (e%12)*8;
        us8 xv = *(const us8*)(xb + xbase + (size_t)c*HW + w8);
        us8 o;
        #pragma unroll
        for(int j=0;j<8;j++) o[j] = f2bu(g*T[c][w8+j] + us2f(xv[j]));
        *(us8*)(ob + xbase + (size_t)c*HW + w8) = o;
      }
    }
  } else {
    const float* xb = (const float*)x;
    float* ob = (float*)out;
    #pragma unroll
    for(int i=0;i<3;i++){
      int e = i*512 + tid;            // 0..1535 (64c x 24 float4-chunks)
      int c = e/24, w4 = (e%24)*4;
      float4 xv = *(const float4*)(xb + xbase + (size_t)c*HW + w4);
      float4 tv = *(const float4*)&T[c][w4];
      float4 o;
      o.x = g*tv.x + xv.x;
      o.y = g*tv.y + xv.y;
      o.z = g*tv.z + xv.z;
      o.w = g*tv.w + xv.w;
      *(float4*)(ob + xbase + (size_t)c*HW + w4) = o;
    }
  }
}

extern "C" void kernel_launch(void* const* d_in, const int* in_sizes, int n_in,
                              void* d_out, int out_size, void* d_ws, size_t ws_size,
                              hipStream_t stream){
  (void)in_sizes; (void)n_in; (void)out_size; (void)ws_size;
  const void* x     = d_in[0];
  const void* Wq    = d_in[1];
  const void* bq    = d_in[2];
  const void* Wk    = d_in[3];
  const void* bk    = d_in[4];
  const void* Wv    = d_in[5];
  const void* bv    = d_in[6];
  const void* gamma = d_in[7];
  char* ws = (char*)d_ws;

  // workspace layout (bytes), total 199229440:
  //   [0, 655360)            Wall  (640x512 bf16)
  //   [655360, 657920)       ball  (640 f32)
  //   [657920, 657924)       flag  (int)
  //   [1MiB, +94371840)      Ot    (8 x 9216 x 640 bf16)   q|k|v position-major
  //   [95420416, +28311552)  att   (8 x 9216 x 192 bf16)
  //   [123731968, +75497472) xT    (8 x 9216 x 512 bf16)   -- dead after k_qkv
  //   [123731968, +28311552) eh2   (8 x 9216 x 96 f32)     -- overlaps xT, dead after k_ewsm
  //   [123731968, +75497472) P     (8 x 9216 x 512 bf16)   -- holds out_h partial
  bf16*  Wall = (bf16*)(ws + 0);
  float* ball = (float*)(ws + 655360);
  int*   flag = (int*)(ws + 657920);
  bf16*  Ot   = (bf16*)(ws + (1u<<20));
  bf16*  att  = (bf16*)(ws + 95420416ull);
  bf16*  xT   = (bf16*)(ws + 123731968ull);
  float* eh2  = (float*)(ws + 123731968ull);
  bf16*  P    = (bf16*)(ws + 123731968ull);

  hipLaunchKernelGGL(k_detect, dim3(1),       dim3(256), 0, stream,
                     (const unsigned int*)x, flag);
  hipLaunchKernelGGL(k_pack,   dim3(640),     dim3(256), 0, stream,
                     Wq, Wk, Wv, bq, bk, bv, flag, Wall, ball);
  hipLaunchKernelGGL(k_xcvt,   dim3(144,8,8), dim3(256), 0, stream, x, flag, xT);
  hipLaunchKernelGGL(k_qkv,    dim3(360,8),   dim3(256), 0, stream, xT, Wall, ball, Ot);
  hipLaunchKernelGGL(k_eh,     dim3(96,8),    dim3(384), 0, stream, Ot, eh2);
  hipLaunchKernelGGL(k_ewsm,   dim3(96,8),    dim3(384), 0, stream, Ot, eh2, att);
  hipLaunchKernelGGL(k_outh,   dim3(384,8),   dim3(384), 0, stream, Ot, att, P);
  hipLaunchKernelGGL(k_outwf,  dim3(768,8),   dim3(512), 0, stream,
                     Ot, att, P, x, gamma, flag, d_out);
}

// Round 15
// 271.751 us; speedup vs baseline: 1.1076x; 1.1076x over previous
//
#include <hip/hip_runtime.h>
#include <hip/hip_bf16.h>

typedef __hip_bfloat16 bf16;
typedef unsigned short us8 __attribute__((ext_vector_type(8)));
typedef __attribute__((ext_vector_type(8))) short short8v;
typedef __attribute__((ext_vector_type(4))) float float4v;

__device__ __forceinline__ float us2f(unsigned short u){
  return __uint_as_float(((unsigned int)u) << 16);
}
__device__ __forceinline__ float b2f(bf16 v){ return __bfloat162float(v); }
__device__ __forceinline__ bf16 f2b(float v){ return __float2bfloat16(v); }
__device__ __forceinline__ unsigned short f2bu(float v){
  bf16 t = f2b(v); return *reinterpret_cast<unsigned short*>(&t);
}

#define HW 9216
#define CH 512
#define NQ 640   /* 64 q | 64 k | 512 v packed along output-channel axis */

// -------- dtype detector: flag=1 if x is bf16-packed, 0 if f32 ------------
__global__ void k_detect(const unsigned int* __restrict__ xw, int* __restrict__ flag){
  int t = threadIdx.x;    // 256 threads, 1 block
  int cnt = 0;
  for(int i=t;i<4096;i+=256){
    unsigned e = (xw[i]>>8)&0x7F;
    if(e==0x3E||e==0x3F) cnt++;
  }
  #pragma unroll
  for(int o=32;o>0;o>>=1) cnt += __shfl_xor(cnt,o);
  __shared__ int s[4];
  if((t&63)==0) s[t>>6]=cnt;
  __syncthreads();
  if(t==0){ int tot=s[0]+s[1]+s[2]+s[3]; *flag = (tot > 1228) ? 1 : 0; }
}

// ---------------- pack Wq|Wk|Wv (640x512) + f32 biases ----------------
__global__ void k_pack(const void* __restrict__ Wq, const void* __restrict__ Wk,
                       const void* __restrict__ Wv, const void* __restrict__ bq,
                       const void* __restrict__ bk, const void* __restrict__ bv,
                       const int* __restrict__ flag,
                       bf16* __restrict__ Wall, float* __restrict__ ball){
  bool isbf = (*flag)!=0;
  int j = blockIdx.x, t = threadIdx.x;
  const void* src = (j < 64) ? Wq : (j < 128) ? Wk : Wv;
  int row = (j < 64) ? j : (j < 128) ? (j-64) : (j-128);
  for(int c=t;c<512;c+=256){
    float v = isbf ? b2f(((const bf16*)src)[(size_t)row*512+c])
                   : ((const float*)src)[(size_t)row*512+c];
    Wall[(size_t)j*512+c] = f2b(v);
  }
  if(t==0){
    const void* bsrc = (j<64)? bq : (j<128)? bk : bv;
    ball[j] = isbf ? b2f(((const bf16*)bsrc)[row]) : ((const float*)bsrc)[row];
  }
}

// ---------------- x[b][c][hw] (f32/bf16) -> xT[b][hw][c] (bf16), vectorized
__global__ __launch_bounds__(256) void k_xcvt(const void* __restrict__ x,
    const int* __restrict__ flag, bf16* __restrict__ xT){
  __shared__ float T[64][65];      // [c][hw]
  bool isbf = (*flag)!=0;
  int b = blockIdx.z, c0 = blockIdx.y*64, hw0 = blockIdx.x*64;
  int tid = threadIdx.x;
  if(isbf){
    const bf16* xb = (const bf16*)x + ((size_t)b*CH + c0)*HW + hw0;
    #pragma unroll
    for(int i=0;i<2;i++){
      int e = i*256 + tid;           // 0..511
      int cc = e>>3, h8 = (e&7)*8;
      us8 v = *(const us8*)(xb + (size_t)cc*HW + h8);
      #pragma unroll
      for(int j=0;j<8;j++) T[cc][h8+j] = us2f(v[j]);
    }
  } else {
    const float* xb = (const float*)x + ((size_t)b*CH + c0)*HW + hw0;
    #pragma unroll
    for(int i=0;i<4;i++){
      int e = i*256 + tid;           // 0..1023
      int cc = e>>4, h4 = (e&15)*4;
      float4 v = *(const float4*)(xb + (size_t)cc*HW + h4);
      T[cc][h4]=v.x; T[cc][h4+1]=v.y; T[cc][h4+2]=v.z; T[cc][h4+3]=v.w;
    }
  }
  __syncthreads();
  bf16* tb = xT + ((size_t)b*HW + hw0)*512 + c0;
  #pragma unroll
  for(int i=0;i<2;i++){
    int e = i*256 + tid;             // 0..511
    int r = e>>3, c8 = (e&7)*8;
    us8 o;
    #pragma unroll
    for(int j=0;j<8;j++) o[j] = f2bu(T[c8+j][r]);
    *(us8*)(tb + (size_t)r*512 + c8) = o;
  }
}

// ---------------- QKV GEMM (MFMA): Ot[b][hw][j] = sum_c xT[hw][c]*Wall[j][c]+b[j]
// M=9216 N=640 K=512; tile 128x128x64; 256 thr = 4 waves (2x2), each 64x64
__global__ __launch_bounds__(256) void k_qkv(const bf16* __restrict__ xT,
    const bf16* __restrict__ Wall, const float* __restrict__ ball,
    bf16* __restrict__ Ot){
  __shared__ ushort As[128][72];   // [m][k]
  __shared__ ushort Bs[128][72];   // [n][k]
  int b = blockIdx.y;
  int bx = blockIdx.x;                 // 0..359
  int swz = (bx & 7)*45 + (bx >> 3);   // XCD-chunk: 5 n-siblings stay on one XCD
  int m0 = (swz/5)*128;
  int n0 = (swz%5)*128;
  int tid = threadIdx.x, wid = tid>>6, lane = tid&63;
  int m0w = (wid>>1)*64, n0w = (wid&1)*64;
  const bf16* Ab = xT + ((size_t)b*HW + m0)*512;
  const bf16* Bb = Wall + (size_t)n0*512;
  float4v acc[4][4];
  #pragma unroll
  for(int mt=0;mt<4;mt++)
    #pragma unroll
    for(int nt=0;nt<4;nt++) acc[mt][nt] = (float4v){0.f,0.f,0.f,0.f};
  for(int k0=0;k0<512;k0+=64){
    #pragma unroll
    for(int i=0;i<4;i++){
      int s = tid + i*256;
      int row = s>>3, ko = (s&7)*8;
      us8 v = *(const us8*)(Ab + (size_t)row*512 + k0 + ko);
      *(us8*)&As[row][ko] = v;
      us8 w = *(const us8*)(Bb + (size_t)row*512 + k0 + ko);
      *(us8*)&Bs[row][ko] = w;
    }
    __syncthreads();
    #pragma unroll
    for(int kk=0;kk<64;kk+=32){
      short8v a[4], bb[4];
      #pragma unroll
      for(int mt=0;mt<4;mt++) a[mt] = *(short8v*)&As[m0w+mt*16+(lane&15)][kk+8*(lane>>4)];
      #pragma unroll
      for(int nt=0;nt<4;nt++) bb[nt] = *(short8v*)&Bs[n0w+nt*16+(lane&15)][kk+8*(lane>>4)];
      #pragma unroll
      for(int mt=0;mt<4;mt++)
        #pragma unroll
        for(int nt=0;nt<4;nt++)
          acc[mt][nt] = __builtin_amdgcn_mfma_f32_16x16x32_bf16(a[mt], bb[nt], acc[mt][nt], 0,0,0);
    }
    __syncthreads();
  }
  #pragma unroll
  for(int mt=0;mt<4;mt++){
    #pragma unroll
    for(int nt=0;nt<4;nt++){
      int nn = n0 + n0w + nt*16 + (lane&15);
      float bias = ball[nn];
      int mbase = m0 + m0w + mt*16 + (lane>>4)*4;
      #pragma unroll
      for(int r=0;r<4;r++)
        Ot[((size_t)b*HW + mbase + r)*640 + nn] = f2b(acc[mt][nt][r] + bias);
    }
  }
}

// ---- e_h (MFMA) per (b,w): eh2[(h*96+w)][g] = q(h,w).k(g,w), diag=-inf ----
// M=96(h) N=96(g) K=64; rows of Ot strided by 96*640; 384 thr = 6 waves
__global__ __launch_bounds__(384) void k_eh(const bf16* __restrict__ Ot,
                                            float* __restrict__ eh2){
  __shared__ ushort Qs[96][72];
  __shared__ ushort Ks[96][72];
  int b = blockIdx.y, w = blockIdx.x;
  int tid = threadIdx.x, wid = tid>>6, lane = tid&63;
  const bf16* qb = Ot + ((size_t)b*HW + w)*640;
  #pragma unroll
  for(int i=0;i<2;i++){
    int e = tid + i*384;             // 0..767
    int row = e>>3, ko = (e&7)*8;
    us8 q = *(const us8*)(qb + (size_t)row*96*640 + ko);
    *(us8*)&Qs[row][ko] = q;
    us8 k = *(const us8*)(qb + (size_t)row*96*640 + 64 + ko);
    *(us8*)&Ks[row][ko] = k;
  }
  __syncthreads();
  float4v acc[6];
  #pragma unroll
  for(int nt=0;nt<6;nt++) acc[nt] = (float4v){0.f,0.f,0.f,0.f};
  #pragma unroll
  for(int kt=0;kt<2;kt++){
    int kb = kt*32 + 8*(lane>>4);
    short8v a = *(short8v*)&Qs[wid*16 + (lane&15)][kb];
    #pragma unroll
    for(int nt=0;nt<6;nt++){
      short8v bb = *(short8v*)&Ks[nt*16 + (lane&15)][kb];
      acc[nt] = __builtin_amdgcn_mfma_f32_16x16x32_bf16(a, bb, acc[nt], 0,0,0);
    }
  }
  int hbase = wid*16 + (lane>>4)*4;
  #pragma unroll
  for(int nt=0;nt<6;nt++){
    int g = nt*16 + (lane&15);
    #pragma unroll
    for(int r=0;r<4;r++){
      int h = hbase + r;
      eh2[((size_t)b*HW + (size_t)h*96 + w)*96 + g] =
          (g==h) ? -INFINITY : acc[nt][r];
    }
  }
}

// ---- fused e_w + softmax per (b,h): e_w in LDS, e_h from compact buffer ---
// M=96(w) N=96(v) K=64 MFMA, then row-softmax over [e_h(96) | e_w(96)].
// LDS union: Qs+Ks (27.6KB, dead after MFMA) overlap Ew (38.4KB) -> 4 blk/CU.
__global__ __launch_bounds__(384) void k_ewsm(const bf16* __restrict__ Ot,
    const float* __restrict__ eh2, bf16* __restrict__ att){
  __shared__ char smem[38400];
  ushort (*Qs)[72] = (ushort(*)[72])smem;            // 13824 B
  ushort (*Ks)[72] = (ushort(*)[72])(smem + 13824);  // 13824 B
  float  (*Ew)[100] = (float(*)[100])smem;           // 38400 B (reuses all)
  int b = blockIdx.y, h = blockIdx.x;
  int tid = threadIdx.x, wid = tid>>6, lane = tid&63;
  const bf16* qb = Ot + ((size_t)b*HW + (size_t)h*96)*640;
  #pragma unroll
  for(int i=0;i<2;i++){
    int e = tid + i*384;             // 0..767
    int row = e>>3, ko = (e&7)*8;
    us8 q = *(const us8*)(qb + (size_t)row*640 + ko);
    *(us8*)&Qs[row][ko] = q;
    us8 k = *(const us8*)(qb + (size_t)row*640 + 64 + ko);
    *(us8*)&Ks[row][ko] = k;
  }
  __syncthreads();
  float4v acc[6];
  #pragma unroll
  for(int nt=0;nt<6;nt++) acc[nt] = (float4v){0.f,0.f,0.f,0.f};
  #pragma unroll
  for(int kt=0;kt<2;kt++){
    int kb = kt*32 + 8*(lane>>4);
    short8v a = *(short8v*)&Qs[wid*16 + (lane&15)][kb];
    #pragma unroll
    for(int nt=0;nt<6;nt++){
      short8v bb = *(short8v*)&Ks[nt*16 + (lane&15)][kb];
      acc[nt] = __builtin_amdgcn_mfma_f32_16x16x32_bf16(a, bb, acc[nt], 0,0,0);
    }
  }
  __syncthreads();                   // all waves done READING Qs/Ks
  int wbase = wid*16 + (lane>>4)*4;
  #pragma unroll
  for(int nt=0;nt<6;nt++){
    int v = nt*16 + (lane&15);
    #pragma unroll
    for(int r=0;r<4;r++) Ew[wbase+r][v] = acc[nt][r];
  }
  __syncthreads();
  const float* ehb = eh2 + ((size_t)b*HW + (size_t)h*96)*96;
  bf16* ab = att + ((size_t)b*HW + (size_t)h*96)*192;
  for(int r=0;r<16;r++){
    int w = wid*16 + r;
    const float* er = ehb + (size_t)w*96;
    float v0 = er[lane];
    float v1 = (lane<32) ? er[64+lane] : Ew[w][lane-32];
    float v2 = Ew[w][lane+32];
    float m = fmaxf(fmaxf(v0,v1),v2);
    #pragma unroll
    for(int o=32;o>0;o>>=1) m = fmaxf(m, __shfl_xor(m,o));
    v0=__expf(v0-m); v1=__expf(v1-m); v2=__expf(v2-m);
    float s = v0+v1+v2;
    #pragma unroll
    for(int o=32;o>0;o>>=1) s += __shfl_xor(s,o);
    float inv = 1.0f/s;
    bf16* a = ab + (size_t)w*192;
    a[lane]=f2b(v0*inv); a[lane+64]=f2b(v1*inv); a[lane+128]=f2b(v2*inv);
  }
}

// ---- out_h (MFMA): P[b][h*96+w][c] = sum_g a_h[(h,w)][g] * V[(g,w)][c] ----
// per (b,w,c-quarter): M=96(h) N=128(c) K=96(g); pure store (no RMW).
// Block map w=bx%96, cq=bx/96: the 4 cq-siblings sharing the att slice land
// on the SAME XCD (ids congruent mod 8).
__global__ __launch_bounds__(384) void k_outh(const bf16* __restrict__ Ot,
    const bf16* __restrict__ att, bf16* __restrict__ P){
  __shared__ ushort As[96][104];    // [h][g]
  __shared__ ushort Bs[128][104];   // [c][g]
  int b = blockIdx.y;
  int bx = blockIdx.x;
  int w = bx % 96, c0 = (bx / 96)*128;
  int tid = threadIdx.x, wid = tid>>6, lane = tid&63;
  const bf16* ab = att + ((size_t)b*HW + w)*192;
  #pragma unroll
  for(int i=0;i<3;i++){
    int s = tid + i*384;
    int row = s/12, ko = (s%12)*8;
    us8 v = *(const us8*)(ab + (size_t)row*96*192 + ko);
    *(us8*)&As[row][ko] = v;
  }
  const bf16* vb = Ot + ((size_t)b*HW + w)*640 + 128 + c0;
  #pragma unroll
  for(int i=0;i<4;i++){
    int s = tid + i*384;              // 0..1535
    int g = s % 96, cc = s / 96;      // g-row, c-chunk
    us8 v = *(const us8*)(vb + (size_t)g*96*640 + cc*8);
    #pragma unroll
    for(int j=0;j<8;j++) Bs[cc*8+j][g] = v[j];
  }
  __syncthreads();
  float4v acc[8];
  #pragma unroll
  for(int nt=0;nt<8;nt++) acc[nt] = (float4v){0.f,0.f,0.f,0.f};
  #pragma unroll
  for(int kt=0;kt<3;kt++){
    int kb = kt*32 + 8*(lane>>4);
    short8v a = *(short8v*)&As[wid*16 + (lane&15)][kb];
    #pragma unroll
    for(int nt=0;nt<8;nt++){
      short8v bb = *(short8v*)&Bs[nt*16 + (lane&15)][kb];
      acc[nt] = __builtin_amdgcn_mfma_f32_16x16x32_bf16(a, bb, acc[nt], 0,0,0);
    }
  }
  bf16* Pb = P + ((size_t)b*HW + w)*512 + c0;
  int mb = wid*16 + (lane>>4)*4;
  #pragma unroll
  for(int nt=0;nt<8;nt++){
    int n = nt*16 + (lane&15);
    #pragma unroll
    for(int r=0;r<4;r++){
      size_t o = (size_t)(mb + r)*96*512 + n;
      Pb[o] = f2b(acc[nt][r]);
    }
  }
}

// ---- out_w + final fused (swapped-operand MFMA + LDS epilogue) ------------
// per (b,h,c-EIGHTH): M=64(c) N=96(w) K=96(v); 512 thr = 8 waves (4c x 2w).
// As/Bs LDS-staged (r13 feed); block map h=bx%96, ce=bx/96 keeps the 8
// c-eighth siblings (sharing att+V) on the SAME XCD.  LDS 33.3KB -> 4 blk/CU.
__global__ __launch_bounds__(512) void k_outwf(const bf16* __restrict__ Ot,
    const bf16* __restrict__ att, const bf16* __restrict__ P,
    const void* __restrict__ x, const void* __restrict__ gamma,
    const int* __restrict__ flag, void* __restrict__ out){
  __shared__ char smem[33280];       // A: As(19968)+Bs(13312); B/C: T(25600)
  ushort (*As)[104] = (ushort(*)[104])smem;            // [w][v]  (a_w)
  ushort (*Bs)[104] = (ushort(*)[104])(smem + 19968);  // [c][v]  (V^T, 64 rows)
  float  (*T)[100]  = (float(*)[100])smem;             // [c][w]  epilogue tile
  bool isbf = (*flag)!=0;
  int b = blockIdx.y;
  int bx = blockIdx.x;
  int h = bx % 96, c0 = (bx / 96)*64;   // XCD-affinity for c-siblings
  int tid = threadIdx.x, wid = tid>>6, lane = tid&63;
  float g = isbf ? b2f(((const bf16*)gamma)[0]) : ((const float*)gamma)[0];
  const bf16* ab = att + ((size_t)b*HW + (size_t)h*96)*192 + 96;
  #pragma unroll
  for(int i=0;i<3;i++){
    int s = tid + i*512;
    if(s < 1152){
      int row = s/12, ko = (s%12)*8;
      us8 v = *(const us8*)(ab + (size_t)row*192 + ko);
      *(us8*)&As[row][ko] = v;
    }
  }
  const bf16* vb = Ot + ((size_t)b*HW + (size_t)h*96)*640 + 128 + c0;
  #pragma unroll
  for(int i=0;i<2;i++){
    int s = tid + i*512;              // 0..1023
    if(s < 768){
      int gg = s % 96, cc = s / 96;   // v-row, c-chunk (conflict-free scatter)
      us8 v = *(const us8*)(vb + (size_t)gg*640 + cc*8);
      #pragma unroll
      for(int j=0;j<8;j++) Bs[cc*8+j][gg] = v[j];
    }
  }
  __syncthreads();
  // Phase A: MFMA, wave = (c-tile wid>>1, w-half wid&1); acc[3]
  int mrow = (wid>>1)*16 + (lane&15);
  int ncol0 = (wid&1)*48;
  float4v acc[3];
  #pragma unroll
  for(int nt=0;nt<3;nt++) acc[nt] = (float4v){0.f,0.f,0.f,0.f};
  #pragma unroll
  for(int kt=0;kt<3;kt++){
    int kb = kt*32 + 8*(lane>>4);
    short8v a = *(short8v*)&Bs[mrow][kb];                 // A = V^T (c rows)
    #pragma unroll
    for(int nt=0;nt<3;nt++){
      short8v bb = *(short8v*)&As[ncol0 + nt*16 + (lane&15)][kb]; // B = a_w
      acc[nt] = __builtin_amdgcn_mfma_f32_16x16x32_bf16(a, bb, acc[nt], 0,0,0);
    }
  }
  __syncthreads();                    // As/Bs dead; smem becomes T
  // B1: acc -> T[c][w]
  int clb = (wid>>1)*16 + (lane>>4)*4;
  #pragma unroll
  for(int nt=0;nt<3;nt++){
    int w = ncol0 + nt*16 + (lane&15);
    #pragma unroll
    for(int r=0;r<4;r++) T[clb + r][w] = acc[nt][r];
  }
  __syncthreads();
  // B2: T += P_h (us8 reads, conflict-free scatter-add)
  const bf16* Pb = P + ((size_t)b*HW + (size_t)h*96)*512 + c0;
  #pragma unroll
  for(int i=0;i<2;i++){
    int s = tid + i*512;
    if(s < 768){
      int gg = s % 96, cc = s / 96;   // w-row, c-chunk
      us8 v = *(const us8*)(Pb + (size_t)gg*512 + cc*8);
      #pragma unroll
      for(int j=0;j<8;j++) T[cc*8+j][gg] += us2f(v[j]);
    }
  }
  __syncthreads();
  // C: coalesced write-out  out[b][c0+c][h*96+w] = g*T[c][w] + x[...]
  size_t xbase = ((size_t)b*CH + c0)*HW + (size_t)h*96;
  if(isbf){
    const bf16* xb = (const bf16*)x;
    bf16* ob = (bf16*)out;
    #pragma unroll
    for(int i=0;i<2;i++){
      int e = i*512 + tid;            // 0..1023 (64c x 12 us8-chunks = 768)
      if(e < 768){
        int c = e/12, w8 = (e%12)*8;
        us8 xv = *(const us8*)(xb + xbase + (size_t)c*HW + w8);
        us8 o;
        #pragma unroll
        for(int j=0;j<8;j++) o[j] = f2bu(g*T[c][w8+j] + us2f(xv[j]));
        *(us8*)(ob + xbase + (size_t)c*HW + w8) = o;
      }
    }
  } else {
    const float* xb = (const float*)x;
    float* ob = (float*)out;
    #pragma unroll
    for(int i=0;i<3;i++){
      int e = i*512 + tid;            // 0..1535 (64c x 24 float4-chunks)
      int c = e/24, w4 = (e%24)*4;
      float4 xv = *(const float4*)(xb + xbase + (size_t)c*HW + w4);
      float4 tv = *(const float4*)&T[c][w4];
      float4 o;
      o.x = g*tv.x + xv.x;
      o.y = g*tv.y + xv.y;
      o.z = g*tv.z + xv.z;
      o.w = g*tv.w + xv.w;
      *(float4*)(ob + xbase + (size_t)c*HW + w4) = o;
    }
  }
}

extern "C" void kernel_launch(void* const* d_in, const int* in_sizes, int n_in,
                              void* d_out, int out_size, void* d_ws, size_t ws_size,
                              hipStream_t stream){
  (void)in_sizes; (void)n_in; (void)out_size; (void)ws_size;
  const void* x     = d_in[0];
  const void* Wq    = d_in[1];
  const void* bq    = d_in[2];
  const void* Wk    = d_in[3];
  const void* bk    = d_in[4];
  const void* Wv    = d_in[5];
  const void* bv    = d_in[6];
  const void* gamma = d_in[7];
  char* ws = (char*)d_ws;

  // workspace layout (bytes), total 199229440:
  //   [0, 655360)            Wall  (640x512 bf16)
  //   [655360, 657920)       ball  (640 f32)
  //   [657920, 657924)       flag  (int)
  //   [1MiB, +94371840)      Ot    (8 x 9216 x 640 bf16)   q|k|v position-major
  //   [95420416, +28311552)  att   (8 x 9216 x 192 bf16)
  //   [123731968, +75497472) xT    (8 x 9216 x 512 bf16)   -- dead after k_qkv
  //   [123731968, +28311552) eh2   (8 x 9216 x 96 f32)     -- overlaps xT, dead after k_ewsm
  //   [123731968, +75497472) P     (8 x 9216 x 512 bf16)   -- holds out_h partial
  bf16*  Wall = (bf16*)(ws + 0);
  float* ball = (float*)(ws + 655360);
  int*   flag = (int*)(ws + 657920);
  bf16*  Ot   = (bf16*)(ws + (1u<<20));
  bf16*  att  = (bf16*)(ws + 95420416ull);
  bf16*  xT   = (bf16*)(ws + 123731968ull);
  float* eh2  = (float*)(ws + 123731968ull);
  bf16*  P    = (bf16*)(ws + 123731968ull);

  hipLaunchKernelGGL(k_detect, dim3(1),       dim3(256), 0, stream,
                     (const unsigned int*)x, flag);
  hipLaunchKernelGGL(k_pack,   dim3(640),     dim3(256), 0, stream,
                     Wq, Wk, Wv, bq, bk, bv, flag, Wall, ball);
  hipLaunchKernelGGL(k_xcvt,   dim3(144,8,8), dim3(256), 0, stream, x, flag, xT);
  hipLaunchKernelGGL(k_qkv,    dim3(360,8),   dim3(256), 0, stream, xT, Wall, ball, Ot);
  hipLaunchKernelGGL(k_eh,     dim3(96,8),    dim3(384), 0, stream, Ot, eh2);
  hipLaunchKernelGGL(k_ewsm,   dim3(96,8),    dim3(384), 0, stream, Ot, eh2, att);
  hipLaunchKernelGGL(k_outh,   dim3(384,8),   dim3(384), 0, stream, Ot, att, P);
  hipLaunchKernelGGL(k_outwf,  dim3(768,8),   dim3(512), 0, stream,
                     Ot, att, P, x, gamma, flag, d_out);
}

// Round 16
// 268.824 us; speedup vs baseline: 1.1197x; 1.0109x over previous
//
#include <hip/hip_runtime.h>
#include <hip/hip_bf16.h>

typedef __hip_bfloat16 bf16;
typedef unsigned short us8 __attribute__((ext_vector_type(8)));
typedef __attribute__((ext_vector_type(8))) short short8v;
typedef __attribute__((ext_vector_type(4))) float float4v;

__device__ __forceinline__ float us2f(unsigned short u){
  return __uint_as_float(((unsigned int)u) << 16);
}
__device__ __forceinline__ float b2f(bf16 v){ return __bfloat162float(v); }
__device__ __forceinline__ bf16 f2b(float v){ return __float2bfloat16(v); }
__device__ __forceinline__ unsigned short f2bu(float v){
  bf16 t = f2b(v); return *reinterpret_cast<unsigned short*>(&t);
}
__device__ __forceinline__ void gload16(const void* g, void* l){
  __builtin_amdgcn_global_load_lds((const __attribute__((address_space(1))) void*)g,
                                   (__attribute__((address_space(3))) void*)l, 16, 0, 0);
}

#define HW 9216
#define CH 512
#define NQ 640   /* 64 q | 64 k | 512 v packed along output-channel axis */

// -------- dtype detector: flag=1 if x is bf16-packed, 0 if f32 ------------
__global__ void k_detect(const unsigned int* __restrict__ xw, int* __restrict__ flag){
  int t = threadIdx.x;    // 256 threads, 1 block
  int cnt = 0;
  for(int i=t;i<4096;i+=256){
    unsigned e = (xw[i]>>8)&0x7F;
    if(e==0x3E||e==0x3F) cnt++;
  }
  #pragma unroll
  for(int o=32;o>0;o>>=1) cnt += __shfl_xor(cnt,o);
  __shared__ int s[4];
  if((t&63)==0) s[t>>6]=cnt;
  __syncthreads();
  if(t==0){ int tot=s[0]+s[1]+s[2]+s[3]; *flag = (tot > 1228) ? 1 : 0; }
}

// ---------------- pack Wq|Wk|Wv (640x512) + f32 biases ----------------
__global__ void k_pack(const void* __restrict__ Wq, const void* __restrict__ Wk,
                       const void* __restrict__ Wv, const void* __restrict__ bq,
                       const void* __restrict__ bk, const void* __restrict__ bv,
                       const int* __restrict__ flag,
                       bf16* __restrict__ Wall, float* __restrict__ ball){
  bool isbf = (*flag)!=0;
  int j = blockIdx.x, t = threadIdx.x;
  const void* src = (j < 64) ? Wq : (j < 128) ? Wk : Wv;
  int row = (j < 64) ? j : (j < 128) ? (j-64) : (j-128);
  for(int c=t;c<512;c+=256){
    float v = isbf ? b2f(((const bf16*)src)[(size_t)row*512+c])
                   : ((const float*)src)[(size_t)row*512+c];
    Wall[(size_t)j*512+c] = f2b(v);
  }
  if(t==0){
    const void* bsrc = (j<64)? bq : (j<128)? bk : bv;
    ball[j] = isbf ? b2f(((const bf16*)bsrc)[row]) : ((const float*)bsrc)[row];
  }
}

// ---------------- x[b][c][hw] (f32/bf16) -> xT[b][hw][c] (bf16), vectorized
__global__ __launch_bounds__(256) void k_xcvt(const void* __restrict__ x,
    const int* __restrict__ flag, bf16* __restrict__ xT){
  __shared__ float T[64][65];      // [c][hw]
  bool isbf = (*flag)!=0;
  int b = blockIdx.z, c0 = blockIdx.y*64, hw0 = blockIdx.x*64;
  int tid = threadIdx.x;
  if(isbf){
    const bf16* xb = (const bf16*)x + ((size_t)b*CH + c0)*HW + hw0;
    #pragma unroll
    for(int i=0;i<2;i++){
      int e = i*256 + tid;           // 0..511
      int cc = e>>3, h8 = (e&7)*8;
      us8 v = *(const us8*)(xb + (size_t)cc*HW + h8);
      #pragma unroll
      for(int j=0;j<8;j++) T[cc][h8+j] = us2f(v[j]);
    }
  } else {
    const float* xb = (const float*)x + ((size_t)b*CH + c0)*HW + hw0;
    #pragma unroll
    for(int i=0;i<4;i++){
      int e = i*256 + tid;           // 0..1023
      int cc = e>>4, h4 = (e&15)*4;
      float4 v = *(const float4*)(xb + (size_t)cc*HW + h4);
      T[cc][h4]=v.x; T[cc][h4+1]=v.y; T[cc][h4+2]=v.z; T[cc][h4+3]=v.w;
    }
  }
  __syncthreads();
  bf16* tb = xT + ((size_t)b*HW + hw0)*512 + c0;
  #pragma unroll
  for(int i=0;i<2;i++){
    int e = i*256 + tid;             // 0..511
    int r = e>>3, c8 = (e&7)*8;
    us8 o;
    #pragma unroll
    for(int j=0;j<8;j++) o[j] = f2bu(T[c8+j][r]);
    *(us8*)(tb + (size_t)r*512 + c8) = o;
  }
}

// ---------------- QKV GEMM (MFMA): Ot[b][hw][j] = sum_c xT[hw][c]*Wall[j][c]+b[j]
// M=9216 N=640 K=512; tile 128x128x64; 4 waves (2x2), each 64x64.
// Staging via global_load_lds (linear LDS) with both-sides XOR swizzle
// (r8 variant, verified bit-identical):
//   linear byte (row*128 + p) holds source col-byte (p ^ ((row&7)<<4));
//   reads XOR the same pattern -> 2-way banks (free), no ds_write VALU.
__global__ __launch_bounds__(256) void k_qkv(const bf16* __restrict__ xT,
    const bf16* __restrict__ Wall, const float* __restrict__ ball,
    bf16* __restrict__ Ot){
  __shared__ ushort AsL[128*64];   // 16 KB, linear [row][64]
  __shared__ ushort BsL[128*64];
  int b = blockIdx.y;
  int bx = blockIdx.x;                 // 0..359
  int swz = (bx & 7)*45 + (bx >> 3);   // XCD-chunk: 5 n-siblings stay on one XCD
  int m0 = (swz/5)*128;
  int n0 = (swz%5)*128;
  int tid = threadIdx.x, wid = tid>>6, lane = tid&63;
  int m0w = (wid>>1)*64, n0w = (wid&1)*64;
  const bf16* Ab = xT + ((size_t)b*HW + m0)*512;
  const bf16* Bb = Wall + (size_t)n0*512;
  int r8 = lane>>3, c8 = lane&7;
  int csw = ((c8 ^ r8)*8);             // pre-swizzled source col (bf16 units)
  float4v acc[4][4];
  #pragma unroll
  for(int mt=0;mt<4;mt++)
    #pragma unroll
    for(int nt=0;nt<4;nt++) acc[mt][nt] = (float4v){0.f,0.f,0.f,0.f};
  for(int k0=0;k0<512;k0+=64){
    #pragma unroll
    for(int j=0;j<4;j++){
      int row0 = (j*4 + wid)*8;        // wave-uniform, 8 rows per call
      gload16(Ab + (size_t)(row0 + r8)*512 + k0 + csw, &AsL[row0*64]);
      gload16(Bb + (size_t)(row0 + r8)*512 + k0 + csw, &BsL[row0*64]);
    }
    __syncthreads();                   // drains vmcnt incl. global_load_lds
    #pragma unroll
    for(int kk=0;kk<64;kk+=32){
      short8v a[4], bb[4];
      #pragma unroll
      for(int mt=0;mt<4;mt++){
        int row = m0w + mt*16 + (lane&15);
        int kb = (kk*2 + 16*(lane>>4)) ^ ((row&7)<<4);
        a[mt] = *(const short8v*)((const char*)AsL + row*128 + kb);
      }
      #pragma unroll
      for(int nt=0;nt<4;nt++){
        int row = n0w + nt*16 + (lane&15);
        int kb = (kk*2 + 16*(lane>>4)) ^ ((row&7)<<4);
        bb[nt] = *(const short8v*)((const char*)BsL + row*128 + kb);
      }
      #pragma unroll
      for(int mt=0;mt<4;mt++)
        #pragma unroll
        for(int nt=0;nt<4;nt++)
          acc[mt][nt] = __builtin_amdgcn_mfma_f32_16x16x32_bf16(a[mt], bb[nt], acc[mt][nt], 0,0,0);
    }
    __syncthreads();
  }
  #pragma unroll
  for(int mt=0;mt<4;mt++){
    #pragma unroll
    for(int nt=0;nt<4;nt++){
      int nn = n0 + n0w + nt*16 + (lane&15);
      float bias = ball[nn];
      int mbase = m0 + m0w + mt*16 + (lane>>4)*4;
      #pragma unroll
      for(int r=0;r<4;r++)
        Ot[((size_t)b*HW + mbase + r)*640 + nn] = f2b(acc[mt][nt][r] + bias);
    }
  }
}

// ---- e_h (MFMA) per (b,w): eh2[(h*96+w)][g] = q(h,w).k(g,w), diag=-inf ----
// M=96(h) N=96(g) K=64; rows of Ot strided by 96*640; 384 thr = 6 waves
__global__ __launch_bounds__(384) void k_eh(const bf16* __restrict__ Ot,
                                            float* __restrict__ eh2){
  __shared__ ushort Qs[96][72];
  __shared__ ushort Ks[96][72];
  int b = blockIdx.y, w = blockIdx.x;
  int tid = threadIdx.x, wid = tid>>6, lane = tid&63;
  const bf16* qb = Ot + ((size_t)b*HW + w)*640;
  #pragma unroll
  for(int i=0;i<2;i++){
    int e = tid + i*384;             // 0..767
    int row = e>>3, ko = (e&7)*8;
    us8 q = *(const us8*)(qb + (size_t)row*96*640 + ko);
    *(us8*)&Qs[row][ko] = q;
    us8 k = *(const us8*)(qb + (size_t)row*96*640 + 64 + ko);
    *(us8*)&Ks[row][ko] = k;
  }
  __syncthreads();
  float4v acc[6];
  #pragma unroll
  for(int nt=0;nt<6;nt++) acc[nt] = (float4v){0.f,0.f,0.f,0.f};
  #pragma unroll
  for(int kt=0;kt<2;kt++){
    int kb = kt*32 + 8*(lane>>4);
    short8v a = *(short8v*)&Qs[wid*16 + (lane&15)][kb];
    #pragma unroll
    for(int nt=0;nt<6;nt++){
      short8v bb = *(short8v*)&Ks[nt*16 + (lane&15)][kb];
      acc[nt] = __builtin_amdgcn_mfma_f32_16x16x32_bf16(a, bb, acc[nt], 0,0,0);
    }
  }
  int hbase = wid*16 + (lane>>4)*4;
  #pragma unroll
  for(int nt=0;nt<6;nt++){
    int g = nt*16 + (lane&15);
    #pragma unroll
    for(int r=0;r<4;r++){
      int h = hbase + r;
      eh2[((size_t)b*HW + (size_t)h*96 + w)*96 + g] =
          (g==h) ? -INFINITY : acc[nt][r];
    }
  }
}

// ---- fused e_w + softmax per (b,h): e_w in LDS, e_h from compact buffer ---
// M=96(w) N=96(v) K=64 MFMA, then row-softmax over [e_h(96) | e_w(96)].
// LDS union: Qs+Ks (27.6KB, dead after MFMA) overlap Ew (38.4KB) -> 4 blk/CU.
__global__ __launch_bounds__(384) void k_ewsm(const bf16* __restrict__ Ot,
    const float* __restrict__ eh2, bf16* __restrict__ att){
  __shared__ char smem[38400];
  ushort (*Qs)[72] = (ushort(*)[72])smem;            // 13824 B
  ushort (*Ks)[72] = (ushort(*)[72])(smem + 13824);  // 13824 B
  float  (*Ew)[100] = (float(*)[100])smem;           // 38400 B (reuses all)
  int b = blockIdx.y, h = blockIdx.x;
  int tid = threadIdx.x, wid = tid>>6, lane = tid&63;
  const bf16* qb = Ot + ((size_t)b*HW + (size_t)h*96)*640;
  #pragma unroll
  for(int i=0;i<2;i++){
    int e = tid + i*384;             // 0..767
    int row = e>>3, ko = (e&7)*8;
    us8 q = *(const us8*)(qb + (size_t)row*640 + ko);
    *(us8*)&Qs[row][ko] = q;
    us8 k = *(const us8*)(qb + (size_t)row*640 + 64 + ko);
    *(us8*)&Ks[row][ko] = k;
  }
  __syncthreads();
  float4v acc[6];
  #pragma unroll
  for(int nt=0;nt<6;nt++) acc[nt] = (float4v){0.f,0.f,0.f,0.f};
  #pragma unroll
  for(int kt=0;kt<2;kt++){
    int kb = kt*32 + 8*(lane>>4);
    short8v a = *(short8v*)&Qs[wid*16 + (lane&15)][kb];
    #pragma unroll
    for(int nt=0;nt<6;nt++){
      short8v bb = *(short8v*)&Ks[nt*16 + (lane&15)][kb];
      acc[nt] = __builtin_amdgcn_mfma_f32_16x16x32_bf16(a, bb, acc[nt], 0,0,0);
    }
  }
  __syncthreads();                   // all waves done READING Qs/Ks
  int wbase = wid*16 + (lane>>4)*4;
  #pragma unroll
  for(int nt=0;nt<6;nt++){
    int v = nt*16 + (lane&15);
    #pragma unroll
    for(int r=0;r<4;r++) Ew[wbase+r][v] = acc[nt][r];
  }
  __syncthreads();
  const float* ehb = eh2 + ((size_t)b*HW + (size_t)h*96)*96;
  bf16* ab = att + ((size_t)b*HW + (size_t)h*96)*192;
  for(int r=0;r<16;r++){
    int w = wid*16 + r;
    const float* er = ehb + (size_t)w*96;
    float v0 = er[lane];
    float v1 = (lane<32) ? er[64+lane] : Ew[w][lane-32];
    float v2 = Ew[w][lane+32];
    float m = fmaxf(fmaxf(v0,v1),v2);
    #pragma unroll
    for(int o=32;o>0;o>>=1) m = fmaxf(m, __shfl_xor(m,o));
    v0=__expf(v0-m); v1=__expf(v1-m); v2=__expf(v2-m);
    float s = v0+v1+v2;
    #pragma unroll
    for(int o=32;o>0;o>>=1) s += __shfl_xor(s,o);
    float inv = 1.0f/s;
    bf16* a = ab + (size_t)w*192;
    a[lane]=f2b(v0*inv); a[lane+64]=f2b(v1*inv); a[lane+128]=f2b(v2*inv);
  }
}

// ---- out_h (MFMA): P[b][h*96+w][c] = sum_g a_h[(h,w)][g] * V[(g,w)][c] ----
// per (b,w,c-quarter): M=96(h) N=128(c) K=96(g); pure store (no RMW).
// Block map w=bx%96, cq=bx/96: the 4 cq-siblings sharing the att slice land
// on the SAME XCD (ids congruent mod 8).
__global__ __launch_bounds__(384) void k_outh(const bf16* __restrict__ Ot,
    const bf16* __restrict__ att, bf16* __restrict__ P){
  __shared__ ushort As[96][104];    // [h][g]
  __shared__ ushort Bs[128][104];   // [c][g]
  int b = blockIdx.y;
  int bx = blockIdx.x;
  int w = bx % 96, c0 = (bx / 96)*128;
  int tid = threadIdx.x, wid = tid>>6, lane = tid&63;
  const bf16* ab = att + ((size_t)b*HW + w)*192;
  #pragma unroll
  for(int i=0;i<3;i++){
    int s = tid + i*384;
    int row = s/12, ko = (s%12)*8;
    us8 v = *(const us8*)(ab + (size_t)row*96*192 + ko);
    *(us8*)&As[row][ko] = v;
  }
  const bf16* vb = Ot + ((size_t)b*HW + w)*640 + 128 + c0;
  #pragma unroll
  for(int i=0;i<4;i++){
    int s = tid + i*384;              // 0..1535
    int g = s % 96, cc = s / 96;      // g-row, c-chunk
    us8 v = *(const us8*)(vb + (size_t)g*96*640 + cc*8);
    #pragma unroll
    for(int j=0;j<8;j++) Bs[cc*8+j][g] = v[j];
  }
  __syncthreads();
  float4v acc[8];
  #pragma unroll
  for(int nt=0;nt<8;nt++) acc[nt] = (float4v){0.f,0.f,0.f,0.f};
  #pragma unroll
  for(int kt=0;kt<3;kt++){
    int kb = kt*32 + 8*(lane>>4);
    short8v a = *(short8v*)&As[wid*16 + (lane&15)][kb];
    #pragma unroll
    for(int nt=0;nt<8;nt++){
      short8v bb = *(short8v*)&Bs[nt*16 + (lane&15)][kb];
      acc[nt] = __builtin_amdgcn_mfma_f32_16x16x32_bf16(a, bb, acc[nt], 0,0,0);
    }
  }
  bf16* Pb = P + ((size_t)b*HW + w)*512 + c0;
  int mb = wid*16 + (lane>>4)*4;
  #pragma unroll
  for(int nt=0;nt<8;nt++){
    int n = nt*16 + (lane&15);
    #pragma unroll
    for(int r=0;r<4;r++){
      size_t o = (size_t)(mb + r)*96*512 + n;
      Pb[o] = f2b(acc[nt][r]);
    }
  }
}

// ---- out_w + final fused (swapped-operand MFMA + LDS epilogue) ------------
// per (b,h,c-EIGHTH): M=64(c) N=96(w) K=96(v); 512 thr = 8 waves (4c x 2w).
// As/Bs LDS-staged; block map h=bx%96, ce=bx/96 keeps the 8 c-eighth
// siblings (sharing att+V) on the SAME XCD.  LDS 33.3KB -> 4 blk/CU.
__global__ __launch_bounds__(512) void k_outwf(const bf16* __restrict__ Ot,
    const bf16* __restrict__ att, const bf16* __restrict__ P,
    const void* __restrict__ x, const void* __restrict__ gamma,
    const int* __restrict__ flag, void* __restrict__ out){
  __shared__ char smem[33280];       // A: As(19968)+Bs(13312); B/C: T(25600)
  ushort (*As)[104] = (ushort(*)[104])smem;            // [w][v]  (a_w)
  ushort (*Bs)[104] = (ushort(*)[104])(smem + 19968);  // [c][v]  (V^T, 64 rows)
  float  (*T)[100]  = (float(*)[100])smem;             // [c][w]  epilogue tile
  bool isbf = (*flag)!=0;
  int b = blockIdx.y;
  int bx = blockIdx.x;
  int h = bx % 96, c0 = (bx / 96)*64;   // XCD-affinity for c-siblings
  int tid = threadIdx.x, wid = tid>>6, lane = tid&63;
  float g = isbf ? b2f(((const bf16*)gamma)[0]) : ((const float*)gamma)[0];
  const bf16* ab = att + ((size_t)b*HW + (size_t)h*96)*192 + 96;
  #pragma unroll
  for(int i=0;i<3;i++){
    int s = tid + i*512;
    if(s < 1152){
      int row = s/12, ko = (s%12)*8;
      us8 v = *(const us8*)(ab + (size_t)row*192 + ko);
      *(us8*)&As[row][ko] = v;
    }
  }
  const bf16* vb = Ot + ((size_t)b*HW + (size_t)h*96)*640 + 128 + c0;
  #pragma unroll
  for(int i=0;i<2;i++){
    int s = tid + i*512;              // 0..1023
    if(s < 768){
      int gg = s % 96, cc = s / 96;   // v-row, c-chunk (conflict-free scatter)
      us8 v = *(const us8*)(vb + (size_t)gg*640 + cc*8);
      #pragma unroll
      for(int j=0;j<8;j++) Bs[cc*8+j][gg] = v[j];
    }
  }
  __syncthreads();
  // Phase A: MFMA, wave = (c-tile wid>>1, w-half wid&1); acc[3]
  int mrow = (wid>>1)*16 + (lane&15);
  int ncol0 = (wid&1)*48;
  float4v acc[3];
  #pragma unroll
  for(int nt=0;nt<3;nt++) acc[nt] = (float4v){0.f,0.f,0.f,0.f};
  #pragma unroll
  for(int kt=0;kt<3;kt++){
    int kb = kt*32 + 8*(lane>>4);
    short8v a = *(short8v*)&Bs[mrow][kb];                 // A = V^T (c rows)
    #pragma unroll
    for(int nt=0;nt<3;nt++){
      short8v bb = *(short8v*)&As[ncol0 + nt*16 + (lane&15)][kb]; // B = a_w
      acc[nt] = __builtin_amdgcn_mfma_f32_16x16x32_bf16(a, bb, acc[nt], 0,0,0);
    }
  }
  __syncthreads();                    // As/Bs dead; smem becomes T
  // B1: acc -> T[c][w]
  int clb = (wid>>1)*16 + (lane>>4)*4;
  #pragma unroll
  for(int nt=0;nt<3;nt++){
    int w = ncol0 + nt*16 + (lane&15);
    #pragma unroll
    for(int r=0;r<4;r++) T[clb + r][w] = acc[nt][r];
  }
  __syncthreads();
  // B2: T += P_h (us8 reads, conflict-free scatter-add)
  const bf16* Pb = P + ((size_t)b*HW + (size_t)h*96)*512 + c0;
  #pragma unroll
  for(int i=0;i<2;i++){
    int s = tid + i*512;
    if(s < 768){
      int gg = s % 96, cc = s / 96;   // w-row, c-chunk
      us8 v = *(const us8*)(Pb + (size_t)gg*512 + cc*8);
      #pragma unroll
      for(int j=0;j<8;j++) T[cc*8+j][gg] += us2f(v[j]);
    }
  }
  __syncthreads();
  // C: coalesced write-out  out[b][c0+c][h*96+w] = g*T[c][w] + x[...]
  size_t xbase = ((size_t)b*CH + c0)*HW + (size_t)h*96;
  if(isbf){
    const bf16* xb = (const bf16*)x;
    bf16* ob = (bf16*)out;
    #pragma unroll
    for(int i=0;i<2;i++){
      int e = i*512 + tid;            // 0..1023 (64c x 12 us8-chunks = 768)
      if(e < 768){
        int c = e/12, w8 = (e%12)*8;
        us8 xv = *(const us8*)(xb + xbase + (size_t)c*HW + w8);
        us8 o;
        #pragma unroll
        for(int j=0;j<8;j++) o[j] = f2bu(g*T[c][w8+j] + us2f(xv[j]));
        *(us8*)(ob + xbase + (size_t)c*HW + w8) = o;
      }
    }
  } else {
    const float* xb = (const float*)x;
    float* ob = (float*)out;
    #pragma unroll
    for(int i=0;i<3;i++){
      int e = i*512 + tid;            // 0..1535 (64c x 24 float4-chunks)
      int c = e/24, w4 = (e%24)*4;
      float4 xv = *(const float4*)(xb + xbase + (size_t)c*HW + w4);
      float4 tv = *(const float4*)&T[c][w4];
      float4 o;
      o.x = g*tv.x + xv.x;
      o.y = g*tv.y + xv.y;
      o.z = g*tv.z + xv.z;
      o.w = g*tv.w + xv.w;
      *(float4*)(ob + xbase + (size_t)c*HW + w4) = o;
    }
  }
}

extern "C" void kernel_launch(void* const* d_in, const int* in_sizes, int n_in,
                              void* d_out, int out_size, void* d_ws, size_t ws_size,
                              hipStream_t stream){
  (void)in_sizes; (void)n_in; (void)out_size; (void)ws_size;
  const void* x     = d_in[0];
  const void* Wq    = d_in[1];
  const void* bq    = d_in[2];
  const void* Wk    = d_in[3];
  const void* bk    = d_in[4];
  const void* Wv    = d_in[5];
  const void* bv    = d_in[6];
  const void* gamma = d_in[7];
  char* ws = (char*)d_ws;

  // workspace layout (bytes), total 199229440:
  //   [0, 655360)            Wall  (640x512 bf16)
  //   [655360, 657920)       ball  (640 f32)
  //   [657920, 657924)       flag  (int)
  //   [1MiB, +94371840)      Ot    (8 x 9216 x 640 bf16)   q|k|v position-major
  //   [95420416, +28311552)  att   (8 x 9216 x 192 bf16)
  //   [123731968, +75497472) xT    (8 x 9216 x 512 bf16)   -- dead after k_qkv
  //   [123731968, +28311552) eh2   (8 x 9216 x 96 f32)     -- overlaps xT, dead after k_ewsm
  //   [123731968, +75497472) P     (8 x 9216 x 512 bf16)   -- holds out_h partial
  bf16*  Wall = (bf16*)(ws + 0);
  float* ball = (float*)(ws + 655360);
  int*   flag = (int*)(ws + 657920);
  bf16*  Ot   = (bf16*)(ws + (1u<<20));
  bf16*  att  = (bf16*)(ws + 95420416ull);
  bf16*  xT   = (bf16*)(ws + 123731968ull);
  float* eh2  = (float*)(ws + 123731968ull);
  bf16*  P    = (bf16*)(ws + 123731968ull);

  hipLaunchKernelGGL(k_detect, dim3(1),       dim3(256), 0, stream,
                     (const unsigned int*)x, flag);
  hipLaunchKernelGGL(k_pack,   dim3(640),     dim3(256), 0, stream,
                     Wq, Wk, Wv, bq, bk, bv, flag, Wall, ball);
  hipLaunchKernelGGL(k_xcvt,   dim3(144,8,8), dim3(256), 0, stream, x, flag, xT);
  hipLaunchKernelGGL(k_qkv,    dim3(360,8),   dim3(256), 0, stream, xT, Wall, ball, Ot);
  hipLaunchKernelGGL(k_eh,     dim3(96,8),    dim3(384), 0, stream, Ot, eh2);
  hipLaunchKernelGGL(k_ewsm,   dim3(96,8),    dim3(384), 0, stream, Ot, eh2, att);
  hipLaunchKernelGGL(k_outh,   dim3(384,8),   dim3(384), 0, stream, Ot, att, P);
  hipLaunchKernelGGL(k_outwf,  dim3(768,8),   dim3(512), 0, stream,
                     Ot, att, P, x, gamma, flag, d_out);
}